// Round 18
// baseline (133.179 us; speedup 1.0000x reference)
//
#include <hip/hip_runtime.h>

typedef _Float16 half8 __attribute__((ext_vector_type(8)));
typedef _Float16 half4 __attribute__((ext_vector_type(4)));
typedef _Float16 half2 __attribute__((ext_vector_type(2)));
typedef __fp16  fp16x2 __attribute__((ext_vector_type(2)));
typedef float f32x4 __attribute__((ext_vector_type(4)));
typedef float f32x16 __attribute__((ext_vector_type(16)));
typedef unsigned int uint2v __attribute__((ext_vector_type(2)));

static __device__ __forceinline__ half2 cvt_pk(float a, float b) {
    fp16x2 r = __builtin_amdgcn_cvt_pkrtz(a, b);
    return __builtin_bit_cast(half2, r);
}
static __device__ __forceinline__ float fdot2_acc(half2 a, half2 b, float c) {
    return __builtin_amdgcn_fdot2(__builtin_bit_cast(fp16x2, a),
                                  __builtin_bit_cast(fp16x2, b), c, false);
}
// lane l gets v from lane l^32. permlane32_swap(vdst,src0): vdst.row1 <-> src0.row0.
// With both inputs = v: r.x = {l<32: own, l>=32: v[l-32]}, r.y = {l<32: v[l+32], l>=32: own}.
// Partner value: hi ? r.x : r.y.
static __device__ __forceinline__ unsigned swap32u(unsigned v, int hi) {
    uint2v r = __builtin_amdgcn_permlane32_swap(v, v, false, false);
    return hi ? r.x : r.y;
}
static __device__ __forceinline__ float swap32f(float v, int hi) {
    return __builtin_bit_cast(float, swap32u(__builtin_bit_cast(unsigned, v), hi));
}

// B=8, L1=L2=1024, D_IN=768, H=12, DK=DV=64, M=B*L=8192

// ---------------------------------------------------------------------------
// One-time W transpose+convert: Wt[z][n][k] fp16 = W_z[k][n] fp32, z in {q,k,v}
// ---------------------------------------------------------------------------
__global__ __launch_bounds__(256)
void wtrans_kernel(const float* __restrict__ Wq, const float* __restrict__ Wk,
                   const float* __restrict__ Wv, _Float16* __restrict__ Wt)
{
    __shared__ float t[32][33];
    const float* W = (blockIdx.z == 0) ? Wq : (blockIdx.z == 1) ? Wk : Wv;
    _Float16* dst = Wt + blockIdx.z * 768 * 768;
    const int tx = threadIdx.x & 31, ty = threadIdx.x >> 5;
    const int k0 = blockIdx.y * 32, n0 = blockIdx.x * 32;
    #pragma unroll
    for (int i = 0; i < 4; ++i)
        t[ty + 8 * i][tx] = W[(k0 + ty + 8 * i) * 768 + n0 + tx];
    __syncthreads();
    #pragma unroll
    for (int i = 0; i < 4; ++i)
        dst[(n0 + ty + 8 * i) * 768 + k0 + tx] = (_Float16)t[tx][ty + 8 * i];
}

// ---------------------------------------------------------------------------
// projKV (XCD-swizzled): isv=0: K = y@Wk+bk; isv=1: V = y@Wv+bv -> Vt
// ---------------------------------------------------------------------------
__global__ __launch_bounds__(256)
void projKV_kernel(const float* __restrict__ A, const _Float16* __restrict__ Wt,
                   const float* __restrict__ bk, const float* __restrict__ bv,
                   _Float16* __restrict__ kout, _Float16* __restrict__ vout)
{
    __shared__ __align__(16) char smem[34816];
    _Float16* const Alds = (_Float16*)smem;            // [128][40] padded
    _Float16* const Wlds = (_Float16*)smem + 128 * 40; // [128][40]
    _Float16* const Tlds = (_Float16*)smem;            // [128][136] epilogue

    const int tid  = threadIdx.x;
    const int lane = tid & 63;
    const int wave = tid >> 6;
    const int lr = lane & 15, lg = lane >> 4;
    const int wm = wave >> 1, wn = wave & 1;

    const int bid = blockIdx.x;                        // 0..767
    const int lid = (bid & 7) * 96 + (bid >> 3);
    const int m0  = (lid / 12) * 128;
    const int rem = lid % 12;
    const int n0  = (rem % 6) * 128;
    const int isv = rem / 6;

    const _Float16* __restrict__ W = Wt + (1 + isv) * 768 * 768;
    const float* __restrict__ bias = isv ? bv : bk;

    f32x4 acc[4][4] = {};

    const int ar   = tid >> 3;
    const int ac   = (tid & 7) * 4;
    const int wrow = tid >> 1;
    const int wcb  = (tid & 1) * 16;

    for (int kb = 0; kb < 24; ++kb) {
        #pragma unroll
        for (int i = 0; i < 4; ++i) {
            const int row = ar + 32 * i;
            const float4 v = *(const float4*)(A + (m0 + row) * 768 + kb * 32 + ac);
            half4 hh = { (_Float16)v.x, (_Float16)v.y, (_Float16)v.z, (_Float16)v.w };
            *(half4*)(Alds + row * 40 + ac) = hh;
        }
        {
            const _Float16* wtr = W + (n0 + wrow) * 768 + kb * 32 + wcb;
            *(uint4*)(Wlds + wrow * 40 + wcb)     = *(const uint4*)(wtr);
            *(uint4*)(Wlds + wrow * 40 + wcb + 8) = *(const uint4*)(wtr + 8);
        }
        __syncthreads();

        half8 af[4], bf[4];
        #pragma unroll
        for (int mt = 0; mt < 4; ++mt)
            af[mt] = *(const half8*)(Alds + (wm * 64 + mt * 16 + lr) * 40 + lg * 8);
        #pragma unroll
        for (int nt = 0; nt < 4; ++nt)
            bf[nt] = *(const half8*)(Wlds + (wn * 64 + nt * 16 + lr) * 40 + lg * 8);
        #pragma unroll
        for (int mt = 0; mt < 4; ++mt)
            #pragma unroll
            for (int nt = 0; nt < 4; ++nt)
                acc[mt][nt] = __builtin_amdgcn_mfma_f32_16x16x32_f16(af[mt], bf[nt], acc[mt][nt], 0, 0, 0);
        __syncthreads();
    }

    #pragma unroll
    for (int nt = 0; nt < 4; ++nt) {
        const int col = wn * 64 + nt * 16 + lr;
        const float bs = bias[n0 + col];
        #pragma unroll
        for (int mt = 0; mt < 4; ++mt) {
            #pragma unroll
            for (int r = 0; r < 4; ++r) {
                const int row = wm * 64 + mt * 16 + lg * 4 + r;
                const float val = acc[mt][nt][r] + bs;
                if (isv) Tlds[col * 136 + row] = (_Float16)val;
                else     Tlds[row * 136 + col] = (_Float16)val;
            }
        }
    }
    __syncthreads();

    const int crow = tid >> 1;
    const int cb   = (tid & 1) * 64;
    const _Float16* lsrc = Tlds + crow * 136 + cb;
    _Float16* gdst;
    if (isv) {
        const int bb  = m0 >> 10;
        const int l2b = m0 & 1023;
        gdst = vout + (bb * 768 + n0 + crow) * 1024 + l2b + cb;
    } else {
        gdst = kout + (m0 + crow) * 768 + n0 + cb;
    }
    #pragma unroll
    for (int it = 0; it < 8; ++it)
        *(uint4*)(gdst + it * 8) = *(const uint4*)(lsrc + it * 8);
}

// ---------------------------------------------------------------------------
// projQ (XCD-swizzled): Q = (x@Wq+bq)*0.125 -> [8192][768]
// ---------------------------------------------------------------------------
__global__ __launch_bounds__(256)
void projQ_kernel(const float* __restrict__ x, const _Float16* __restrict__ Wt,
                  const float* __restrict__ bq, _Float16* __restrict__ qout)
{
    __shared__ __align__(16) char smem[34816];
    _Float16* const Alds = (_Float16*)smem;            // [128][40]
    _Float16* const Wlds = (_Float16*)smem + 128 * 40; // [128][40]
    _Float16* const Tlds = (_Float16*)smem;            // [128][136]

    const int tid  = threadIdx.x;
    const int lane = tid & 63;
    const int wave = tid >> 6;
    const int lr = lane & 15, lg = lane >> 4;
    const int wm = wave >> 1, wn = wave & 1;

    const int bid = blockIdx.x;                        // 0..383
    const int lid = (bid & 7) * 48 + (bid >> 3);
    const int m0  = (lid / 6) * 128;
    const int n0  = (lid % 6) * 128;

    const _Float16* __restrict__ W = Wt;               // q slice

    f32x4 acc[4][4] = {};

    const int ar   = tid >> 3;
    const int ac   = (tid & 7) * 4;
    const int wrow = tid >> 1;
    const int wcb  = (tid & 1) * 16;

    for (int kb = 0; kb < 24; ++kb) {
        #pragma unroll
        for (int i = 0; i < 4; ++i) {
            const int row = ar + 32 * i;
            const float4 v = *(const float4*)(x + (m0 + row) * 768 + kb * 32 + ac);
            half4 hh = { (_Float16)v.x, (_Float16)v.y, (_Float16)v.z, (_Float16)v.w };
            *(half4*)(Alds + row * 40 + ac) = hh;
        }
        {
            const _Float16* wtr = W + (n0 + wrow) * 768 + kb * 32 + wcb;
            *(uint4*)(Wlds + wrow * 40 + wcb)     = *(const uint4*)(wtr);
            *(uint4*)(Wlds + wrow * 40 + wcb + 8) = *(const uint4*)(wtr + 8);
        }
        __syncthreads();

        half8 af[4], bf[4];
        #pragma unroll
        for (int mt = 0; mt < 4; ++mt)
            af[mt] = *(const half8*)(Alds + (wm * 64 + mt * 16 + lr) * 40 + lg * 8);
        #pragma unroll
        for (int nt = 0; nt < 4; ++nt)
            bf[nt] = *(const half8*)(Wlds + (wn * 64 + nt * 16 + lr) * 40 + lg * 8);
        #pragma unroll
        for (int mt = 0; mt < 4; ++mt)
            #pragma unroll
            for (int nt = 0; nt < 4; ++nt)
                acc[mt][nt] = __builtin_amdgcn_mfma_f32_16x16x32_f16(af[mt], bf[nt], acc[mt][nt], 0, 0, 0);
        __syncthreads();
    }

    #pragma unroll
    for (int nt = 0; nt < 4; ++nt) {
        const int col = wn * 64 + nt * 16 + lr;
        const float bs = bq[n0 + col];
        #pragma unroll
        for (int mt = 0; mt < 4; ++mt) {
            #pragma unroll
            for (int r = 0; r < 4; ++r) {
                const int row = wm * 64 + mt * 16 + lg * 4 + r;
                Tlds[row * 136 + col] = (_Float16)((acc[mt][nt][r] + bs) * 0.125f);
            }
        }
    }
    __syncthreads();

    const int crow = tid >> 1;
    const int cb   = (tid & 1) * 64;
    const _Float16* lsrc = Tlds + crow * 136 + cb;
    _Float16* gdst = qout + (m0 + crow) * 768 + n0 + cb;
    #pragma unroll
    for (int it = 0; it < 8; ++it)
        *(uint4*)(gdst + it * 8) = *(const uint4*)(lsrc + it * 8);
}

// ---------------------------------------------------------------------------
// Fused attention, 32x32 MFMA, paired-tile (128 kv per barrier pair).
// Block = (q-tile 128), 256 thr / 4 waves, each wave owns 32 q-rows.
// XCD-swizzled grid of 768. In-register P, permlane32_swap exchanges,
// exp2 softmax, defer-max, lane-local l.
// S^T layout (mfma(K,Q)): col q = lane&31, row kv = (r&3)+8(r>>2)+4hi (+32*t).
// ---------------------------------------------------------------------------
template<bool QPRE>
__global__ __launch_bounds__(256, 3)
void attn_kernel(const float* __restrict__ x, const _Float16* __restrict__ Wtq,
                 const float* __restrict__ bq, const _Float16* __restrict__ Qp,
                 const _Float16* __restrict__ K, const _Float16* __restrict__ Vt,
                 const unsigned char* __restrict__ mask,
                 float* __restrict__ out)
{
    __shared__ __align__(16) char smem[QPRE ? 38912 : 57344];
    _Float16* const KA = (_Float16*)smem;              // K buf A [64][72]
    _Float16* const KB = (_Float16*)(smem + 9216);     // K buf B
    _Float16* const VA = (_Float16*)(smem + 18432);    // V buf A
    _Float16* const VB = (_Float16*)(smem + 27648);    // V buf B
    _Float16* const Mh = (_Float16*)(smem + 36864);    // [1024] fp16 0/1

    const int tid  = threadIdx.x;
    const int lane = tid & 63;
    const int wave = tid >> 6;                         // 0..3
    const int l31  = lane & 31;
    const int hi   = lane >> 5;

    const int bid = blockIdx.x;                        // 0..767
    const int lid = (bid & 7) * 96 + (bid >> 3);       // XCD swizzle
    const int q0 = (lid & 7) * 128;
    const int h  = (lid >> 3) % 12;
    const int b  = lid / 96;

    const float C2 = 1.44269504f;       // log2(e)

    if constexpr (!QPRE) {
        // ---- fallback: Q[128][64] = (x@Wq+bq)/8 via 16x16 MFMA, BK=32 ----
        _Float16* const Xl  = (_Float16*)smem;             // [128][72]
        _Float16* const Wl  = (_Float16*)(smem + 18432);   // [64][72]
        _Float16* const QPl = (_Float16*)(smem + 38912);   // [128][72]
        const int lr = lane & 15, lg = lane >> 4;
        const int xr = tid >> 1, xc = (tid & 1) * 16;
        const int wr = tid >> 2, wc = (tid & 3) * 8;
        f32x4 qacc[2][4] = {};
        for (int kb = 0; kb < 24; ++kb) {
            const float* xrow = x + (b * 1024 + q0 + xr) * 768 + kb * 32 + xc;
            const float4 v0 = *(const float4*)(xrow);
            const float4 v1 = *(const float4*)(xrow + 4);
            const float4 v2 = *(const float4*)(xrow + 8);
            const float4 v3 = *(const float4*)(xrow + 12);
            const uint4 wv = *(const uint4*)(Wtq + (h * 64 + wr) * 768 + kb * 32 + wc);
            union { half2 hh[4]; half8 v; } u0, u1;
            u0.hh[0] = cvt_pk(v0.x, v0.y); u0.hh[1] = cvt_pk(v0.z, v0.w);
            u0.hh[2] = cvt_pk(v1.x, v1.y); u0.hh[3] = cvt_pk(v1.z, v1.w);
            u1.hh[0] = cvt_pk(v2.x, v2.y); u1.hh[1] = cvt_pk(v2.z, v2.w);
            u1.hh[2] = cvt_pk(v3.x, v3.y); u1.hh[3] = cvt_pk(v3.z, v3.w);
            *(half8*)(Xl + xr * 72 + xc)     = u0.v;
            *(half8*)(Xl + xr * 72 + xc + 8) = u1.v;
            *(uint4*)(Wl + wr * 72 + wc)     = wv;
            __syncthreads();
            #pragma unroll
            for (int c = 0; c < 2; ++c) {
                const half8 af = *(const half8*)(Xl + (c * 64 + wave * 16 + lr) * 72 + lg * 8);
                #pragma unroll
                for (int nt = 0; nt < 4; ++nt) {
                    const half8 bf = *(const half8*)(Wl + (nt * 16 + lr) * 72 + lg * 8);
                    qacc[c][nt] = __builtin_amdgcn_mfma_f32_16x16x32_f16(af, bf, qacc[c][nt], 0, 0, 0);
                }
            }
            __syncthreads();
        }
        #pragma unroll
        for (int c = 0; c < 2; ++c)
            #pragma unroll
            for (int nt = 0; nt < 4; ++nt) {
                const int d = nt * 16 + lr;
                const float bs = bq[h * 64 + d];
                #pragma unroll
                for (int r = 0; r < 4; ++r)
                    QPl[(c * 64 + wave * 16 + lg * 4 + r) * 72 + d] =
                        (_Float16)((qacc[c][nt][r] + bs) * 0.125f);
            }
        __syncthreads();
    }

    // fp16 multiplicative mask (1 = keep, 0 = masked)
    {
        const uchar4 mk = *(const uchar4*)(mask + b * 1024 + tid * 4);
        half4 mh = { mk.x ? (_Float16)0.f : (_Float16)1.f,
                     mk.y ? (_Float16)0.f : (_Float16)1.f,
                     mk.z ? (_Float16)0.f : (_Float16)1.f,
                     mk.w ? (_Float16)0.f : (_Float16)1.f };
        *(half4*)(Mh + tid * 4) = mh;
    }

    // Q B-fragments (32x32x16): lane holds Q[q = q0+wave*32+l31][d = ks*16+hi*8+j]
    half8 qf[4];
    if constexpr (QPRE) {
        const _Float16* qrp = Qp + (b * 1024 + q0 + wave * 32 + l31) * 768 + h * 64;
        #pragma unroll
        for (int ks = 0; ks < 4; ++ks)
            qf[ks] = *(const half8*)(qrp + ks * 16 + hi * 8);
    } else {
        _Float16* const QPl = (_Float16*)(smem + 38912);
        #pragma unroll
        for (int ks = 0; ks < 4; ++ks)
            qf[ks] = *(const half8*)(QPl + (wave * 32 + l31) * 72 + ks * 16 + hi * 8);
    }

    f32x16 o[2] = {};
    float m_run = -1e30f, l_run = 0.f;
    const half2 one2 = { (_Float16)1.f, (_Float16)1.f };

    const int sr  = tid >> 2;            // 0..63 staging row
    const int sc  = (tid & 3) * 16;      // staging col (16 halves)
    const _Float16* const Kg = K + (b * 1024 + sr) * 768 + h * 64 + sc;
    const _Float16* const Vg = Vt + (b * 768 + h * 64 + sr) * 1024 + sc;

    // softmax+PV for one 64-kv tile whose S lives in (s0, s1)
    auto process = [&](const f32x16& s0, const f32x16& s1, int base0,
                       const _Float16* Vb, float nb) {
        unsigned ql[8], qh[8];
        float ps = 0.f;
        #pragma unroll
        for (int t = 0; t < 2; ++t)
            #pragma unroll
            for (int g = 0; g < 4; ++g) {
                const f32x16& s = t ? s1 : s0;
                half2 pa = cvt_pk(
                    __builtin_amdgcn_exp2f(fmaf(s[4 * g + 0], C2, nb)),
                    __builtin_amdgcn_exp2f(fmaf(s[4 * g + 1], C2, nb)));
                half2 pb = cvt_pk(
                    __builtin_amdgcn_exp2f(fmaf(s[4 * g + 2], C2, nb)),
                    __builtin_amdgcn_exp2f(fmaf(s[4 * g + 3], C2, nb)));
                const half4 mv = *(const half4*)(Mh + base0 + t * 32 + 8 * g + 4 * hi);
                const half2 mk0 = { mv[0], mv[1] };
                const half2 mk1 = { mv[2], mv[3] };
                pa *= mk0;
                pb *= mk1;
                ps = fdot2_acc(pa, one2, ps);
                ps = fdot2_acc(pb, one2, ps);
                ql[4 * t + g] = __builtin_bit_cast(unsigned int, pa);
                qh[4 * t + g] = __builtin_bit_cast(unsigned int, pb);
            }
        l_run += ps;   // lane-local; cross-half reduce once at the end

        __builtin_amdgcn_s_setprio(1);
        #pragma unroll
        for (int ks = 0; ks < 4; ++ks) {
            const unsigned sl = hi ? ql[2 * ks] : ql[2 * ks + 1];
            const unsigned sh = hi ? qh[2 * ks] : qh[2 * ks + 1];
            const unsigned rl = swap32u(sl, hi);
            const unsigned rh = swap32u(sh, hi);
            union { unsigned u[4]; half8 v; } bf;
            bf.u[0] = hi ? rl : ql[2 * ks];
            bf.u[1] = hi ? rh : qh[2 * ks];
            bf.u[2] = hi ? ql[2 * ks + 1] : rl;
            bf.u[3] = hi ? qh[2 * ks + 1] : rh;
            const half8 a0 = *(const half8*)(Vb + l31 * 72 + ks * 16 + hi * 8);
            const half8 a1 = *(const half8*)(Vb + (l31 + 32) * 72 + ks * 16 + hi * 8);
            o[0] = __builtin_amdgcn_mfma_f32_32x32x16_f16(a0, bf.v, o[0], 0, 0, 0);
            o[1] = __builtin_amdgcn_mfma_f32_32x32x16_f16(a1, bf.v, o[1], 0, 0, 0);
        }
        __builtin_amdgcn_s_setprio(0);
    };

    auto compute_pair = [&](int kv0) {
        // QK for both tiles: 4 independent MFMA chains
        f32x16 sa0 = {}, sa1 = {}, sb0 = {}, sb1 = {};
        __builtin_amdgcn_s_setprio(1);
        #pragma unroll
        for (int ks = 0; ks < 4; ++ks) {
            const half8 a0 = *(const half8*)(KA + l31 * 72 + ks * 16 + hi * 8);
            const half8 a1 = *(const half8*)(KA + (l31 + 32) * 72 + ks * 16 + hi * 8);
            const half8 b0 = *(const half8*)(KB + l31 * 72 + ks * 16 + hi * 8);
            const half8 b1 = *(const half8*)(KB + (l31 + 32) * 72 + ks * 16 + hi * 8);
            sa0 = __builtin_amdgcn_mfma_f32_32x32x16_f16(a0, qf[ks], sa0, 0, 0, 0);
            sa1 = __builtin_amdgcn_mfma_f32_32x32x16_f16(a1, qf[ks], sa1, 0, 0, 0);
            sb0 = __builtin_amdgcn_mfma_f32_32x32x16_f16(b0, qf[ks], sb0, 0, 0, 0);
            sb1 = __builtin_amdgcn_mfma_f32_32x32x16_f16(b1, qf[ks], sb1, 0, 0, 0);
        }
        __builtin_amdgcn_s_setprio(0);

        // joint max over 128 kv (max3-friendly tree)
        float t16[16];
        #pragma unroll
        for (int r = 0; r < 16; ++r)
            t16[r] = fmaxf(fmaxf(sa0[r], sa1[r]), fmaxf(sb0[r], sb1[r]));
        #pragma unroll
        for (int w = 8; w >= 1; w >>= 1)
            #pragma unroll
            for (int r = 0; r < w; ++r) t16[r] = fmaxf(t16[r], t16[r + w]);
        float mx = t16[0];
        mx = fmaxf(mx, swap32f(mx, hi));

        if (!__all(mx <= m_run + 8.f)) {
            const float m_new = fmaxf(m_run, mx);
            const float corr = __builtin_amdgcn_exp2f((m_run - m_new) * C2);
            l_run *= corr;
            #pragma unroll
            for (int t = 0; t < 2; ++t)
                #pragma unroll
                for (int r = 0; r < 16; ++r) o[t][r] *= corr;
            m_run = m_new;
        }
        const float nb = -m_run * C2;

        process(sa0, sa1, kv0,      VA, nb);
        process(sb0, sb1, kv0 + 64, VB, nb);
    };

    // register prefetch: tiles 0 (A set) and 1 (B set)
    uint4 ka0, ka1, va0, va1, kb0, kb1, vb0, vb1;
    ka0 = *(const uint4*)(Kg);            ka1 = *(const uint4*)(Kg + 8);
    va0 = *(const uint4*)(Vg);            va1 = *(const uint4*)(Vg + 8);
    kb0 = *(const uint4*)(Kg + 64 * 768); kb1 = *(const uint4*)(Kg + 64 * 768 + 8);
    vb0 = *(const uint4*)(Vg + 64);       vb1 = *(const uint4*)(Vg + 64 + 8);

    for (int j = 0; j < 8; ++j) {
        *(uint4*)(KA + sr * 72 + sc)     = ka0;
        *(uint4*)(KA + sr * 72 + sc + 8) = ka1;
        *(uint4*)(VA + sr * 72 + sc)     = va0;
        *(uint4*)(VA + sr * 72 + sc + 8) = va1;
        *(uint4*)(KB + sr * 72 + sc)     = kb0;
        *(uint4*)(KB + sr * 72 + sc + 8) = kb1;
        *(uint4*)(VB + sr * 72 + sc)     = vb0;
        *(uint4*)(VB + sr * 72 + sc + 8) = vb1;
        if (j < 7) {
            const int ta = (2 * j + 2) * 64, tb = (2 * j + 3) * 64;
            ka0 = *(const uint4*)(Kg + ta * 768);
            ka1 = *(const uint4*)(Kg + ta * 768 + 8);
            va0 = *(const uint4*)(Vg + ta);
            va1 = *(const uint4*)(Vg + ta + 8);
            kb0 = *(const uint4*)(Kg + tb * 768);
            kb1 = *(const uint4*)(Kg + tb * 768 + 8);
            vb0 = *(const uint4*)(Vg + tb);
            vb1 = *(const uint4*)(Vg + tb + 8);
        }
        __syncthreads();               // staging visible to all waves
        compute_pair(j * 128);
        __syncthreads();               // all reads done before next writes
    }

    // final cross-half l reduction, epilogue
    l_run += swap32f(l_run, hi);
    const float inv = 1.f / l_run;
    const int qrow = b * 1024 + q0 + wave * 32 + l31;
    float* od = out + qrow * 768 + h * 64 + 4 * hi;
    #pragma unroll
    for (int dt = 0; dt < 2; ++dt)
        #pragma unroll
        for (int g = 0; g < 4; ++g) {
            float4 v;
            v.x = o[dt][4 * g + 0] * inv;
            v.y = o[dt][4 * g + 1] * inv;
            v.z = o[dt][4 * g + 2] * inv;
            v.w = o[dt][4 * g + 3] * inv;
            *(float4*)(od + dt * 32 + 8 * g) = v;
        }
}

extern "C" void kernel_launch(void* const* d_in, const int* in_sizes, int n_in,
                              void* d_out, int out_size, void* d_ws, size_t ws_size,
                              hipStream_t stream)
{
    const float* x  = (const float*)d_in[0];
    const float* y  = (const float*)d_in[1];
    const unsigned char* ym = (const unsigned char*)d_in[2];
    const float* Wq = (const float*)d_in[3];
    const float* bq = (const float*)d_in[4];
    const float* Wk = (const float*)d_in[5];
    const float* bk = (const float*)d_in[6];
    const float* Wv = (const float*)d_in[7];
    const float* bv = (const float*)d_in[8];

    _Float16* kws = (_Float16*)d_ws;             // [8192][768] K
    _Float16* vws = kws + 8192 * 768;            // [B][H*DV][L2] V^T
    _Float16* wt  = vws + 8192 * 768;            // [3][768][768] W^T (q,k,v)
    _Float16* qws = wt + 3 * 768 * 768;          // [8192][768] Q (optional)

    const size_t need = (size_t)(3 * 8192 * 768 + 3 * 768 * 768) * sizeof(_Float16);
    const bool qpre = ws_size >= need;

    wtrans_kernel<<<dim3(24, 24, 3), 256, 0, stream>>>(Wq, Wk, Wv, wt);
    projKV_kernel<<<768, 256, 0, stream>>>(y, wt, bk, bv, kws, vws);
    if (qpre) {
        projQ_kernel<<<384, 256, 0, stream>>>(x, wt, bq, qws);
        attn_kernel<true><<<768, 256, 0, stream>>>(
            x, wt, bq, qws, kws, vws, ym, (float*)d_out);
    } else {
        attn_kernel<false><<<768, 256, 0, stream>>>(
            x, wt, bq, qws, kws, vws, ym, (float*)d_out);
    }
}